// Round 9
// baseline (348.855 us; speedup 1.0000x reference)
//
#include <hip/hip_runtime.h>
#include <hip/hip_bf16.h>

#define S_LEN 2048
#define HID   2048
#define NH    16
#define NKV   4
#define HD    128
#define KVD   512            // NKV*HD
#define NQKV  3072           // HID + KVD + KVD
#define SCALE2 0.0078125f    // (D^-0.5)^2 = 1/128
#define NCH   80             // j-chunk slots per head: sum_{qt} ceil((qt+1)/8)

typedef __bf16 bf16;
typedef __attribute__((ext_vector_type(8))) __bf16 bf16x8;
typedef __attribute__((ext_vector_type(4))) float f32x4;

// async global->LDS, 16B per lane; LDS dest is wave-uniform base + lane*16
__device__ __forceinline__ void gload_lds16(const bf16* g, bf16* l) {
    __builtin_amdgcn_global_load_lds((const __attribute__((address_space(1))) void*)g,
                                     (__attribute__((address_space(3))) void*)l, 16, 0, 0);
}

// ---------------------------------------------------------------------------
// Fused pre-pass. Region-decoded grid (all regions independent):
//   [0,2048)     : hs f32 -> hsb bf16
//   [2048,3072)  : Wq transpose-cvt -> WcatT[0]
//   [3072,3328)  : Wk -> WcatT[2048*HID]
//   [3328,3584)  : Wv -> WcatT[2560*HID]
//   [3584,4608)  : Wo -> WoT
//   [4608,6656)  : zero d_out
//   [6656,7168)  : gate projection, one wave per s
//   [7168,10240) : zero qkvf (6M f32 accumulators for split-K qkv)
// ---------------------------------------------------------------------------
__device__ __forceinline__ void transpose_tile(const float* __restrict__ W,
                                               bf16* __restrict__ Wt,
                                               int K, int N, int bx, int by,
                                               int t, float (*Ts)[65])
{
    const int kb = bx * 64, nb = by * 64;
    const int tr = t >> 6, tc = t & 63;
    #pragma unroll
    for (int p = 0; p < 16; ++p) {
        int k = p * 4 + tr;
        Ts[k][tc] = W[(size_t)(kb + k) * N + nb + tc];
    }
    __syncthreads();
    const int nr = t >> 3, kc = t & 7;
    #pragma unroll
    for (int p = 0; p < 2; ++p) {
        int n = p * 32 + nr;
        bf16x8 o;
        #pragma unroll
        for (int x = 0; x < 8; ++x) o[x] = (bf16)Ts[kc * 8 + x][n];
        *(bf16x8*)&Wt[(size_t)(nb + n) * K + kb + kc * 8] = o;
    }
}

__global__ __launch_bounds__(256) void prep_kernel(const float* __restrict__ hs,
                                                   const float* __restrict__ Wq,
                                                   const float* __restrict__ Wk,
                                                   const float* __restrict__ Wv,
                                                   const float* __restrict__ Wo,
                                                   const float* __restrict__ Wg,
                                                   bf16* __restrict__ hsb,
                                                   bf16* __restrict__ WcatT,
                                                   bf16* __restrict__ WoT,
                                                   float* __restrict__ graw,
                                                   float* __restrict__ outz,
                                                   float* __restrict__ qkvf)
{
    __shared__ float Ts[64][65];
    const int b = blockIdx.x, tid = threadIdx.x;

    if (b < 2048) {                                   // cvt hs -> hsb
        int i = (b * 256 + tid) * 8;
        const float4* qp = (const float4*)&hs[i];
        float4 a = qp[0], c = qp[1];
        bf16x8 r;
        r[0]=(bf16)a.x; r[1]=(bf16)a.y; r[2]=(bf16)a.z; r[3]=(bf16)a.w;
        r[4]=(bf16)c.x; r[5]=(bf16)c.y; r[6]=(bf16)c.z; r[7]=(bf16)c.w;
        *(bf16x8*)&hsb[i] = r;
    } else if (b < 3072) {
        int lb = b - 2048;
        transpose_tile(Wq, WcatT, HID, HID, lb >> 5, lb & 31, tid, Ts);
    } else if (b < 3328) {
        int lb = b - 3072;
        transpose_tile(Wk, WcatT + (size_t)2048 * HID, HID, KVD, lb >> 3, lb & 7, tid, Ts);
    } else if (b < 3584) {
        int lb = b - 3328;
        transpose_tile(Wv, WcatT + (size_t)2560 * HID, HID, KVD, lb >> 3, lb & 7, tid, Ts);
    } else if (b < 4608) {
        int lb = b - 3584;
        transpose_tile(Wo, WoT, HID, HID, lb >> 5, lb & 31, tid, Ts);
    } else if (b < 6656) {                            // zero d_out
        int i = ((b - 4608) * 256 + tid) * 8;
        float4 z = make_float4(0.f, 0.f, 0.f, 0.f);
        *(float4*)&outz[i] = z;
        *(float4*)&outz[i + 4] = z;
    } else if (b < 7168) {                            // gproj: wave per s
        const int w = tid >> 6, lane = tid & 63;
        const int s = (b - 6656) * 4 + w;
        float a0 = 0.f, a1 = 0.f, a2 = 0.f, a3 = 0.f;
        for (int kk = lane; kk < HID; kk += 64) {
            float h = hs[(size_t)s * HID + kk];
            const float* wr = &Wg[kk * 4];
            a0 += h * wr[0]; a1 += h * wr[1];
            a2 += h * wr[2]; a3 += h * wr[3];
        }
        #pragma unroll
        for (int off = 32; off >= 1; off >>= 1) {
            a0 += __shfl_xor(a0, off); a1 += __shfl_xor(a1, off);
            a2 += __shfl_xor(a2, off); a3 += __shfl_xor(a3, off);
        }
        if (lane == 0) {
            float vv[4] = {a0, a1, a2, a3};
            #pragma unroll
            for (int c = 0; c < 4; ++c) {
                float x = vv[c];
                graw[c * S_LEN + s] = fminf(x, 0.f) - log1pf(expf(-fabsf(x)));
            }
        }
    } else {                                          // zero qkvf (6M f32)
        int i = ((b - 7168) * 256 + tid) * 8;
        float4 z = make_float4(0.f, 0.f, 0.f, 0.f);
        *(float4*)&qkvf[i] = z;
        *(float4*)&qkvf[i + 4] = z;
    }
}

// ---------------------------------------------------------------------------
// Inclusive cumsum over s per kv head.
// ---------------------------------------------------------------------------
__global__ __launch_bounds__(256) void cumsum_kernel(const float* __restrict__ graw,
                                                     float* __restrict__ G)
{
    int c = blockIdx.x, t = threadIdx.x;
    __shared__ float sums[256];
    float loc[8];
    float run = 0.f;
    #pragma unroll
    for (int i = 0; i < 8; ++i) { run += graw[c * S_LEN + t * 8 + i]; loc[i] = run; }
    sums[t] = run;
    __syncthreads();
    for (int off = 1; off < 256; off <<= 1) {
        float add = (t >= off) ? sums[t - off] : 0.f;
        __syncthreads();
        sums[t] += add;
        __syncthreads();
    }
    float offset = sums[t] - run;
    #pragma unroll
    for (int i = 0; i < 8; ++i) G[c * S_LEN + t * 8 + i] = offset + loc[i];
}

// ---------------------------------------------------------------------------
// m97-style GEMM core loop: 128x128 tile, BK=32, 4 waves, 4x4 MFMA grid.
// ---------------------------------------------------------------------------
__device__ __forceinline__ void gemm128_core(const bf16* __restrict__ A,
                                             const bf16* __restrict__ Bt,
                                             int K, int k0, int k1, int mb, int nb,
                                             bf16 (*As)[32], bf16 (*Bs)[32],
                                             f32x4 (*acc)[4],
                                             int w, int l16, int quad, int lane)
{
    const int m0 = (w & 1) * 64, n0 = (w >> 1) * 64;
    const int srow = lane >> 2, scol = (lane & 3) * 8;

    for (int kt = k0; kt < k1; kt += 32) {
        __syncthreads();
        gload_lds16(&A [(size_t)(mb + w * 32 +      srow) * K + kt + scol], &As[w * 32     ][0]);
        gload_lds16(&A [(size_t)(mb + w * 32 + 16 + srow) * K + kt + scol], &As[w * 32 + 16][0]);
        gload_lds16(&Bt[(size_t)(nb + w * 32 +      srow) * K + kt + scol], &Bs[w * 32     ][0]);
        gload_lds16(&Bt[(size_t)(nb + w * 32 + 16 + srow) * K + kt + scol], &Bs[w * 32 + 16][0]);
        __syncthreads();

        bf16x8 af[4], bfr[4];
        #pragma unroll
        for (int t = 0; t < 4; ++t) af[t]  = *(const bf16x8*)&As[m0 + t * 16 + l16][quad * 8];
        #pragma unroll
        for (int u = 0; u < 4; ++u) bfr[u] = *(const bf16x8*)&Bs[n0 + u * 16 + l16][quad * 8];
        #pragma unroll
        for (int t = 0; t < 4; ++t)
            #pragma unroll
            for (int u = 0; u < 4; ++u)
                acc[t][u] = __builtin_amdgcn_mfma_f32_16x16x32_bf16(af[t], bfr[u], acc[t][u], 0, 0, 0);
    }
}

// Fused QKV projection, split-K=2 over gridDim.z, atomic f32 accumulate into
// pre-zeroed qf/kf/vf. Region bounds are 128-multiples (block-uniform).
__global__ __launch_bounds__(256) void gemm_qkv_kernel(const bf16* __restrict__ A,
                                                       const bf16* __restrict__ Wt,
                                                       float* __restrict__ qf,
                                                       float* __restrict__ kf,
                                                       float* __restrict__ vf,
                                                       int M, int K)
{
    __shared__ __attribute__((aligned(16))) bf16 As[128][32];
    __shared__ __attribute__((aligned(16))) bf16 Bs[128][32];
    const int tid = threadIdx.x, w = tid >> 6, lane = tid & 63;
    const int l16 = lane & 15, quad = lane >> 4;
    const int mb = blockIdx.x * 128, nb = blockIdx.y * 128;
    const int m0 = (w & 1) * 64, n0 = (w >> 1) * 64;
    const int kh = K >> 1, k0 = blockIdx.z * kh;

    f32x4 acc[4][4] = {};
    gemm128_core(A, Wt, K, k0, k0 + kh, mb, nb, As, Bs, acc, w, l16, quad, lane);

    #pragma unroll
    for (int t = 0; t < 4; ++t)
        #pragma unroll
        for (int u = 0; u < 4; ++u)
            #pragma unroll
            for (int r = 0; r < 4; ++r) {
                int row = mb + m0 + t * 16 + quad * 4 + r;
                int col = nb + n0 + u * 16 + l16;
                float val = acc[t][u][r];
                if (nb < 2048)       unsafeAtomicAdd(&qf[(size_t)row * HID + col], val);
                else if (nb < 2560)  unsafeAtomicAdd(&kf[(size_t)row * KVD + (col - 2048)], val);
                else                 unsafeAtomicAdd(&vf[(size_t)(col - 2560) * S_LEN + row], val);
            }
}

// Wo GEMM, split-K=4, atomic f32 accumulate into pre-zeroed out.
__global__ __launch_bounds__(256) void gemm_wo_kernel(const bf16* __restrict__ A,
                                                      const bf16* __restrict__ Bt,
                                                      float* __restrict__ C,
                                                      int M, int N, int K)
{
    __shared__ __attribute__((aligned(16))) bf16 As[128][32];
    __shared__ __attribute__((aligned(16))) bf16 Bs[128][32];
    const int tid = threadIdx.x, w = tid >> 6, lane = tid & 63;
    const int l16 = lane & 15, quad = lane >> 4;
    const int mb = blockIdx.x * 128, nb = blockIdx.y * 128;
    const int m0 = (w & 1) * 64, n0 = (w >> 1) * 64;
    const int kh = K >> 2, k0 = blockIdx.z * kh;

    f32x4 acc[4][4] = {};
    gemm128_core(A, Bt, K, k0, k0 + kh, mb, nb, As, Bs, acc, w, l16, quad, lane);

    #pragma unroll
    for (int t = 0; t < 4; ++t)
        #pragma unroll
        for (int u = 0; u < 4; ++u)
            #pragma unroll
            for (int r = 0; r < 4; ++r) {
                int row = mb + m0 + t * 16 + quad * 4 + r;
                int col = nb + n0 + u * 16 + l16;
                unsafeAtomicAdd(&C[(size_t)row * N + col], acc[t][u][r]);
            }
}

// ---------------------------------------------------------------------------
// Merged RoPE (f32 in, bf16 out) for q and k + v f32->bf16 cvt; region grid.
//   q: thread owns pair (d, d+64) of one (s,h) row of qf -> qbuf
//   k: same on kf -> kbuf
//   v: linear cvt vf -> vT (both [KVD][S_LEN])
// ---------------------------------------------------------------------------
#define RQ_N (S_LEN * NH * 64)
#define RK_N (S_LEN * NKV * 64)
#define RV_N (S_LEN * KVD / 8)
__global__ __launch_bounds__(256) void rope_kernel(const float* __restrict__ qf,
                                                   const float* __restrict__ kf,
                                                   const float* __restrict__ vf,
                                                   bf16* __restrict__ qb,
                                                   bf16* __restrict__ kb,
                                                   bf16* __restrict__ vT,
                                                   const float* __restrict__ cosb,
                                                   const float* __restrict__ sinb)
{
    int idx = blockIdx.x * 256 + threadIdx.x;
    if (idx < RQ_N + RK_N) {
        const float* src; bf16* dst; int s, rem, stride;
        if (idx < RQ_N) {
            src = qf; dst = qb; stride = HID;
            s = idx / (NH * 64); rem = idx % (NH * 64);
        } else {
            idx -= RQ_N;
            src = kf; dst = kb; stride = KVD;
            s = idx / (NKV * 64); rem = idx % (NKV * 64);
        }
        int h = rem >> 6, d = rem & 63;
        size_t base = (size_t)s * stride + h * 128 + d;
        float x0 = src[base], x1 = src[base + 64];
        float c0 = cosb[s * 128 + d], c1 = cosb[s * 128 + d + 64];
        float n0 = sinb[s * 128 + d], n1 = sinb[s * 128 + d + 64];
        dst[base]      = (bf16)(x0 * c0 - x1 * n0);
        dst[base + 64] = (bf16)(x1 * c1 + x0 * n1);
    } else {
        int i = (idx - RQ_N - RK_N) * 8;
        const float4* qp = (const float4*)&vf[i];
        float4 a = qp[0], c = qp[1];
        bf16x8 r;
        r[0]=(bf16)a.x; r[1]=(bf16)a.y; r[2]=(bf16)a.z; r[3]=(bf16)a.w;
        r[4]=(bf16)c.x; r[5]=(bf16)c.y; r[6]=(bf16)c.z; r[7]=(bf16)c.w;
        *(bf16x8*)&vT[i] = r;
    }
}

// ---------------------------------------------------------------------------
// Causal decay attention, j-split. Block = (qt, j-chunk of <=8 tiles, head).
// qt<8 (single chunk): final bf16 out. Else: f32 partial O + partial den.
// ---------------------------------------------------------------------------
__global__ __launch_bounds__(256) void attn_kernel(const bf16* __restrict__ q,
                                                   const bf16* __restrict__ k,
                                                   const bf16* __restrict__ vT,
                                                   const float* __restrict__ G,
                                                   bf16* __restrict__ out,
                                                   float* __restrict__ pO,
                                                   float* __restrict__ pden)
{
    int rem = blockIdx.x, qt = 0, cch = 0;
    #pragma unroll
    for (int g = 0; g < 4; ++g) {
        int sz = 8 * (g + 1);
        if (rem < sz) { qt = g * 8 + rem / (g + 1); cch = rem % (g + 1); break; }
        rem -= sz;
    }
    const int gg = qt >> 3, nc = gg + 1;
    const int jt0 = cch * 8, jt1 = min(qt + 1, jt0 + 8);

    const int h = blockIdx.y, kvh = h >> 2;
    const int qb = qt * 64;
    const int tid = threadIdx.x, w = tid >> 6, lane = tid & 63;
    const int l16 = lane & 15, quad = lane >> 4;

    __shared__ __attribute__((aligned(16))) bf16 Ks4[4][64][32];
    __shared__ __attribute__((aligned(16))) bf16 Vt4[2][128][32];
    __shared__ __attribute__((aligned(16))) bf16 Sb[4][16][68];

    bf16x8 qf[4];
    const int qrow = qb + w * 16 + l16;
    #pragma unroll
    for (int kc = 0; kc < 4; ++kc)
        qf[kc] = *(const bf16x8*)&q[(size_t)qrow * HID + h * HD + kc * 32 + quad * 8];

    const int irow = qb + w * 16 + quad * 4;
    float Gq[4];
    #pragma unroll
    for (int r = 0; r < 4; ++r) Gq[r] = G[kvh * S_LEN + irow + r];

    const int sr4 = lane >> 2, sc4 = (lane & 3) * 8;
    const int vkk = w >> 1, vdg = (w & 1) * 4;

    f32x4 acco[8] = {};
    float den[4] = {0.f, 0.f, 0.f, 0.f};

    for (int kt = jt0; kt < jt1; ++kt) {
        const int jb = kt * 64;
        __syncthreads();
        #pragma unroll
        for (int rg = 0; rg < 4; ++rg)
            gload_lds16(&k[(size_t)(jb + rg * 16 + sr4) * KVD + kvh * HD + w * 32 + sc4],
                        &Ks4[w][rg * 16][0]);
        #pragma unroll
        for (int it = 0; it < 4; ++it)
            gload_lds16(&vT[(size_t)(kvh * HD + (vdg + it) * 16 + sr4) * S_LEN + jb + vkk * 32 + sc4],
                        &Vt4[vkk][(vdg + it) * 16][0]);
        __syncthreads();

        f32x4 accs[4] = {};
        #pragma unroll
        for (int t = 0; t < 4; ++t)
            #pragma unroll
            for (int kc = 0; kc < 4; ++kc) {
                bf16x8 bfr = *(const bf16x8*)&Ks4[kc][t * 16 + l16][quad * 8];
                accs[t] = __builtin_amdgcn_mfma_f32_16x16x32_bf16(qf[kc], bfr, accs[t], 0, 0, 0);
            }

        const float Gt = G[kvh * S_LEN + jb];
        float sr[4];
        #pragma unroll
        for (int r = 0; r < 4; ++r) sr[r] = SCALE2 * __expf(Gq[r] - Gt);
        #pragma unroll
        for (int t = 0; t < 4; ++t) {
            int j = jb + t * 16 + l16;
            float colF = __expf(fminf(Gt - G[kvh * S_LEN + j], 85.f));
            #pragma unroll
            for (int r = 0; r < 4; ++r) {
                float d0 = accs[t][r];
                float sc = (j <= irow + r) ? d0 * d0 * sr[r] * colF : 0.f;
                den[r] += sc;
                Sb[w][quad * 4 + r][t * 16 + l16] = (bf16)sc;
            }
        }
        // no barrier: Sb[w] is wave-private

        #pragma unroll
        for (int kk = 0; kk < 2; ++kk) {
            bf16x8 af = *(const bf16x8*)&Sb[w][l16][kk * 32 + quad * 8];
            #pragma unroll
            for (int dt = 0; dt < 8; ++dt) {
                bf16x8 bfr = *(const bf16x8*)&Vt4[kk][dt * 16 + l16][quad * 8];
                acco[dt] = __builtin_amdgcn_mfma_f32_16x16x32_bf16(af, bfr, acco[dt], 0, 0, 0);
            }
        }
    }

    #pragma unroll
    for (int r = 0; r < 4; ++r) {
        #pragma unroll
        for (int off = 1; off < 16; off <<= 1) den[r] += __shfl_xor(den[r], off);
    }

    if (nc == 1) {
        float dinv[4];
        #pragma unroll
        for (int r = 0; r < 4; ++r) dinv[r] = 1.f / fmaxf(den[r], 1.f);
        #pragma unroll
        for (int dt = 0; dt < 8; ++dt)
            #pragma unroll
            for (int r = 0; r < 4; ++r)
                out[(size_t)(irow + r) * HID + h * HD + dt * 16 + l16] =
                    (bf16)(acco[dt][r] * dinv[r]);
    } else {
        const int slot = h * NCH + 4 * gg * (gg + 1) + (qt & 7) * (gg + 1) + cch;
        float* po = &pO[(size_t)slot * 8192];
        const int lr = w * 16 + quad * 4;
        #pragma unroll
        for (int dt = 0; dt < 8; ++dt)
            #pragma unroll
            for (int r = 0; r < 4; ++r)
                po[(lr + r) * 128 + dt * 16 + l16] = acco[dt][r];
        if (l16 == 0) {
            #pragma unroll
            for (int r = 0; r < 4; ++r) pden[slot * 64 + lr + r] = den[r];
        }
    }
}

// Combine partial chunks for qt >= 8. Grid: 16 heads x 24 qts.
__global__ __launch_bounds__(256) void attn_reduce_kernel(const float* __restrict__ pO,
                                                          const float* __restrict__ pden,
                                                          bf16* __restrict__ out)
{
    const int p = blockIdx.x;
    const int h = p / 24, qt = 8 + p % 24;
    const int gg = qt >> 3, nc = gg + 1;
    const int base = h * NCH + 4 * gg * (gg + 1) + (qt & 7) * (gg + 1);
    const int qb = qt * 64;
    const int tid = threadIdx.x;

    __shared__ float sden[64];
    if (tid < 64) {
        float s = 0.f;
        for (int c = 0; c < nc; ++c) s += pden[(base + c) * 64 + tid];
        sden[tid] = 1.f / fmaxf(s, 1.f);
    }
    __syncthreads();

    #pragma unroll
    for (int i = 0; i < 8; ++i) {
        int e = i * 1024 + tid * 4;
        float4 s = make_float4(0.f, 0.f, 0.f, 0.f);
        for (int c = 0; c < nc; ++c) {
            float4 v = *(const float4*)&pO[(size_t)(base + c) * 8192 + e];
            s.x += v.x; s.y += v.y; s.z += v.z; s.w += v.w;
        }
        int lr = e >> 7, col = e & 127;
        float di = sden[lr];
        bf16* o = &out[(size_t)(qb + lr) * HID + h * HD + col];
        o[0] = (bf16)(s.x * di); o[1] = (bf16)(s.y * di);
        o[2] = (bf16)(s.z * di); o[3] = (bf16)(s.w * di);
    }
}

// ---------------------------------------------------------------------------
extern "C" void kernel_launch(void* const* d_in, const int* in_sizes, int n_in,
                              void* d_out, int out_size, void* d_ws, size_t ws_size,
                              hipStream_t stream)
{
    const float* hs   = (const float*)d_in[0];
    const float* cosb = (const float*)d_in[1];
    const float* sinb = (const float*)d_in[2];
    const float* Wq   = (const float*)d_in[3];
    const float* Wk   = (const float*)d_in[4];
    const float* Wv   = (const float*)d_in[5];
    const float* Wg   = (const float*)d_in[6];
    const float* Wo   = (const float*)d_in[7];
    float* out = (float*)d_out;

    char* p = (char*)d_ws;
    bf16*  qbuf  = (bf16*)p;  p += (size_t)S_LEN * HID * 2;    // 8 MB
    bf16*  kbuf  = (bf16*)p;  p += (size_t)S_LEN * KVD * 2;    // 2 MB
    bf16*  vT    = (bf16*)p;  p += (size_t)S_LEN * KVD * 2;    // 2 MB ([KVD][S])
    bf16*  abuf  = (bf16*)p;  p += (size_t)S_LEN * HID * 2;    // 8 MB
    bf16*  hsb   = (bf16*)p;  p += (size_t)S_LEN * HID * 2;    // 8 MB
    bf16*  WcatT = (bf16*)p;  p += (size_t)NQKV * HID * 2;     // 12 MB
    bf16*  WoT   = (bf16*)p;  p += (size_t)HID * HID * 2;      // 8 MB
    float* graw  = (float*)p; p += (size_t)NKV * S_LEN * 4;
    float* G     = (float*)p; p += (size_t)NKV * S_LEN * 4;
    float* pO    = (float*)p; p += (size_t)NH * NCH * 8192 * 4; // 41.9 MB
    float* pden  = (float*)p; p += (size_t)NH * NCH * 64 * 4;   // 0.33 MB

    // qkv f32 split-K accumulators aliased onto pO (phase-disjoint:
    // zeroed in prep, written by qkv, read by rope — all before attn
    // writes pO). qf 4M + kf 1M + vf 1M floats = 6M <= pO's 10.5M.
    float* qf = pO;
    float* kf = pO + (size_t)4 * 1024 * 1024;
    float* vf = pO + (size_t)5 * 1024 * 1024;

    // 1: fused pre-pass (cvt + transposes + zero out/qkvf + gate projection)
    prep_kernel<<<10240, 256, 0, stream>>>(hs, Wq, Wk, Wv, Wo, Wg,
                                           hsb, WcatT, WoT, graw, out, qf);
    // 2: gate cumsum
    cumsum_kernel<<<NKV, 256, 0, stream>>>(graw, G);
    // 3: fused QKV projection, split-K=2, atomic f32 accumulate
    gemm_qkv_kernel<<<dim3(16, 24, 2), 256, 0, stream>>>(hsb, WcatT, qf, kf, vf, S_LEN, HID);
    // 4: merged RoPE (f32->bf16) for q,k + v cvt
    rope_kernel<<<(RQ_N + RK_N + RV_N) / 256, 256, 0, stream>>>(qf, kf, vf, qbuf, kbuf, vT, cosb, sinb);
    // 5: j-split attention
    attn_kernel<<<dim3(NCH, NH), 256, 0, stream>>>(qbuf, kbuf, vT, G, abuf, pO, pden);
    // 6: combine
    attn_reduce_kernel<<<NH * 24, 256, 0, stream>>>(pO, pden, abuf);
    // 7: output projection (split-K=4, atomic into zeroed out)
    gemm_wo_kernel<<<dim3(16, 16, 4), 256, 0, stream>>>(abuf, WoT, out, S_LEN, HID, HID);
}

// Round 10
// 296.346 us; speedup vs baseline: 1.1772x; 1.1772x over previous
//
#include <hip/hip_runtime.h>
#include <hip/hip_bf16.h>

#define S_LEN 2048
#define HID   2048
#define NH    16
#define NKV   4
#define HD    128
#define KVD   512            // NKV*HD
#define NQKV  3072           // HID + KVD + KVD
#define SCALE2 0.0078125f    // (D^-0.5)^2 = 1/128
#define NCH   80             // j-chunk slots per head: sum_{qt} ceil((qt+1)/8)

typedef __bf16 bf16;
typedef __attribute__((ext_vector_type(8))) __bf16 bf16x8;
typedef __attribute__((ext_vector_type(4))) float f32x4;

// async global->LDS, 16B per lane; LDS dest is wave-uniform base + lane*16
__device__ __forceinline__ void gload_lds16(const bf16* g, bf16* l) {
    __builtin_amdgcn_global_load_lds((const __attribute__((address_space(1))) void*)g,
                                     (__attribute__((address_space(3))) void*)l, 16, 0, 0);
}

// ---------------------------------------------------------------------------
// Fused pre-pass (identical to round 8). Region-decoded grid:
//   [0,2048)    : hs f32 -> hsb bf16
//   [2048,3072) : Wq transpose-cvt -> WcatT[0]
//   [3072,3328) : Wk -> WcatT[2048*HID]
//   [3328,3584) : Wv -> WcatT[2560*HID]
//   [3584,4608) : Wo -> WoT
//   [4608,6656) : zero d_out (for wo atomics)
//   [6656,7168) : gate projection, one wave per s
// ---------------------------------------------------------------------------
__device__ __forceinline__ void transpose_tile(const float* __restrict__ W,
                                               bf16* __restrict__ Wt,
                                               int K, int N, int bx, int by,
                                               int t, float (*Ts)[65])
{
    const int kb = bx * 64, nb = by * 64;
    const int tr = t >> 6, tc = t & 63;
    #pragma unroll
    for (int p = 0; p < 16; ++p) {
        int k = p * 4 + tr;
        Ts[k][tc] = W[(size_t)(kb + k) * N + nb + tc];
    }
    __syncthreads();
    const int nr = t >> 3, kc = t & 7;
    #pragma unroll
    for (int p = 0; p < 2; ++p) {
        int n = p * 32 + nr;
        bf16x8 o;
        #pragma unroll
        for (int x = 0; x < 8; ++x) o[x] = (bf16)Ts[kc * 8 + x][n];
        *(bf16x8*)&Wt[(size_t)(nb + n) * K + kb + kc * 8] = o;
    }
}

__global__ __launch_bounds__(256) void prep_kernel(const float* __restrict__ hs,
                                                   const float* __restrict__ Wq,
                                                   const float* __restrict__ Wk,
                                                   const float* __restrict__ Wv,
                                                   const float* __restrict__ Wo,
                                                   const float* __restrict__ Wg,
                                                   bf16* __restrict__ hsb,
                                                   bf16* __restrict__ WcatT,
                                                   bf16* __restrict__ WoT,
                                                   float* __restrict__ graw,
                                                   float* __restrict__ outz)
{
    __shared__ float Ts[64][65];
    const int b = blockIdx.x, tid = threadIdx.x;

    if (b < 2048) {                                   // cvt hs -> hsb
        int i = (b * 256 + tid) * 8;
        const float4* qp = (const float4*)&hs[i];
        float4 a = qp[0], c = qp[1];
        bf16x8 r;
        r[0]=(bf16)a.x; r[1]=(bf16)a.y; r[2]=(bf16)a.z; r[3]=(bf16)a.w;
        r[4]=(bf16)c.x; r[5]=(bf16)c.y; r[6]=(bf16)c.z; r[7]=(bf16)c.w;
        *(bf16x8*)&hsb[i] = r;
    } else if (b < 3072) {
        int lb = b - 2048;
        transpose_tile(Wq, WcatT, HID, HID, lb >> 5, lb & 31, tid, Ts);
    } else if (b < 3328) {
        int lb = b - 3072;
        transpose_tile(Wk, WcatT + (size_t)2048 * HID, HID, KVD, lb >> 3, lb & 7, tid, Ts);
    } else if (b < 3584) {
        int lb = b - 3328;
        transpose_tile(Wv, WcatT + (size_t)2560 * HID, HID, KVD, lb >> 3, lb & 7, tid, Ts);
    } else if (b < 4608) {
        int lb = b - 3584;
        transpose_tile(Wo, WoT, HID, HID, lb >> 5, lb & 31, tid, Ts);
    } else if (b < 6656) {                            // zero d_out
        int i = ((b - 4608) * 256 + tid) * 8;
        float4 z = make_float4(0.f, 0.f, 0.f, 0.f);
        *(float4*)&outz[i] = z;
        *(float4*)&outz[i + 4] = z;
    } else {                                          // gproj: wave per s
        const int w = tid >> 6, lane = tid & 63;
        const int s = (b - 6656) * 4 + w;
        float a0 = 0.f, a1 = 0.f, a2 = 0.f, a3 = 0.f;
        for (int kk = lane; kk < HID; kk += 64) {
            float h = hs[(size_t)s * HID + kk];
            const float* wr = &Wg[kk * 4];
            a0 += h * wr[0]; a1 += h * wr[1];
            a2 += h * wr[2]; a3 += h * wr[3];
        }
        #pragma unroll
        for (int off = 32; off >= 1; off >>= 1) {
            a0 += __shfl_xor(a0, off); a1 += __shfl_xor(a1, off);
            a2 += __shfl_xor(a2, off); a3 += __shfl_xor(a3, off);
        }
        if (lane == 0) {
            float vv[4] = {a0, a1, a2, a3};
            #pragma unroll
            for (int c = 0; c < 4; ++c) {
                float x = vv[c];
                graw[c * S_LEN + s] = fminf(x, 0.f) - log1pf(expf(-fabsf(x)));
            }
        }
    }
}

// ---------------------------------------------------------------------------
// m97-style GEMM core loop: 128x128 tile, BK=32, 4 waves, 4x4 MFMA grid.
// ---------------------------------------------------------------------------
__device__ __forceinline__ void gemm128_core(const bf16* __restrict__ A,
                                             const bf16* __restrict__ Bt,
                                             int K, int k0, int k1, int mb, int nb,
                                             bf16 (*As)[32], bf16 (*Bs)[32],
                                             f32x4 (*acc)[4],
                                             int w, int l16, int quad, int lane)
{
    const int m0 = (w & 1) * 64, n0 = (w >> 1) * 64;
    const int srow = lane >> 2, scol = (lane & 3) * 8;

    for (int kt = k0; kt < k1; kt += 32) {
        __syncthreads();
        gload_lds16(&A [(size_t)(mb + w * 32 +      srow) * K + kt + scol], &As[w * 32     ][0]);
        gload_lds16(&A [(size_t)(mb + w * 32 + 16 + srow) * K + kt + scol], &As[w * 32 + 16][0]);
        gload_lds16(&Bt[(size_t)(nb + w * 32 +      srow) * K + kt + scol], &Bs[w * 32     ][0]);
        gload_lds16(&Bt[(size_t)(nb + w * 32 + 16 + srow) * K + kt + scol], &Bs[w * 32 + 16][0]);
        __syncthreads();

        bf16x8 af[4], bfr[4];
        #pragma unroll
        for (int t = 0; t < 4; ++t) af[t]  = *(const bf16x8*)&As[m0 + t * 16 + l16][quad * 8];
        #pragma unroll
        for (int u = 0; u < 4; ++u) bfr[u] = *(const bf16x8*)&Bs[n0 + u * 16 + l16][quad * 8];
        #pragma unroll
        for (int t = 0; t < 4; ++t)
            #pragma unroll
            for (int u = 0; u < 4; ++u)
                acc[t][u] = __builtin_amdgcn_mfma_f32_16x16x32_bf16(af[t], bfr[u], acc[t][u], 0, 0, 0);
    }
}

// Fused QKV projection, split-K=2, PLAIN f32 stores into per-z slice buffers
// (no atomics, no zero-init). Slices summed by rope_kernel.
__global__ __launch_bounds__(256) void gemm_qkv_kernel(const bf16* __restrict__ A,
                                                       const bf16* __restrict__ Wt,
                                                       float* __restrict__ qsl,   // [2][S*HID]
                                                       float* __restrict__ ksl,   // [2][S*KVD]
                                                       float* __restrict__ vsl,   // [2][KVD*S] (transposed)
                                                       int M, int K)
{
    __shared__ __attribute__((aligned(16))) bf16 As[128][32];
    __shared__ __attribute__((aligned(16))) bf16 Bs[128][32];
    const int tid = threadIdx.x, w = tid >> 6, lane = tid & 63;
    const int l16 = lane & 15, quad = lane >> 4;
    const int mb = blockIdx.x * 128, nb = blockIdx.y * 128;
    const int m0 = (w & 1) * 64, n0 = (w >> 1) * 64;
    const int z = blockIdx.z, kh = K >> 1, k0 = z * kh;

    float* qd = qsl + (size_t)z * S_LEN * HID;
    float* kd = ksl + (size_t)z * S_LEN * KVD;
    float* vd = vsl + (size_t)z * S_LEN * KVD;

    f32x4 acc[4][4] = {};
    gemm128_core(A, Wt, K, k0, k0 + kh, mb, nb, As, Bs, acc, w, l16, quad, lane);

    #pragma unroll
    for (int t = 0; t < 4; ++t)
        #pragma unroll
        for (int u = 0; u < 4; ++u)
            #pragma unroll
            for (int r = 0; r < 4; ++r) {
                int row = mb + m0 + t * 16 + quad * 4 + r;
                int col = nb + n0 + u * 16 + l16;
                float val = acc[t][u][r];
                if (nb < 2048)       qd[(size_t)row * HID + col] = val;
                else if (nb < 2560)  kd[(size_t)row * KVD + (col - 2048)] = val;
                else                 vd[(size_t)(col - 2560) * S_LEN + row] = val;
            }
}

// Wo GEMM, split-K=2, atomic f32 accumulate into pre-zeroed out (r8-proven).
__global__ __launch_bounds__(256) void gemm_wo_kernel(const bf16* __restrict__ A,
                                                      const bf16* __restrict__ Bt,
                                                      float* __restrict__ C,
                                                      int M, int N, int K)
{
    __shared__ __attribute__((aligned(16))) bf16 As[128][32];
    __shared__ __attribute__((aligned(16))) bf16 Bs[128][32];
    const int tid = threadIdx.x, w = tid >> 6, lane = tid & 63;
    const int l16 = lane & 15, quad = lane >> 4;
    const int mb = blockIdx.x * 128, nb = blockIdx.y * 128;
    const int m0 = (w & 1) * 64, n0 = (w >> 1) * 64;
    const int kh = K >> 1, k0 = blockIdx.z * kh;

    f32x4 acc[4][4] = {};
    gemm128_core(A, Bt, K, k0, k0 + kh, mb, nb, As, Bs, acc, w, l16, quad, lane);

    #pragma unroll
    for (int t = 0; t < 4; ++t)
        #pragma unroll
        for (int u = 0; u < 4; ++u)
            #pragma unroll
            for (int r = 0; r < 4; ++r) {
                int row = mb + m0 + t * 16 + quad * 4 + r;
                int col = nb + n0 + u * 16 + l16;
                unsafeAtomicAdd(&C[(size_t)row * N + col], acc[t][u][r]);
            }
}

// ---------------------------------------------------------------------------
// Merged RoPE: sums the 2 qkv split-K slices (f32), applies rope (q,k) or
// converts (v), writes bf16. Cumsum fused as 4 extra tail blocks.
//   [0, RQB)            : q pairs
//   [RQB, RQB+RKB)      : k pairs
//   [.., +RVB)          : v cvt
//   last 4 blocks       : gate cumsum per kv head
// ---------------------------------------------------------------------------
#define RQB (S_LEN * NH * 64 / 256)     // 8192 blocks
#define RKB (S_LEN * NKV * 64 / 256)    // 2048
#define RVB (S_LEN * KVD / 8 / 256)     // 512
__global__ __launch_bounds__(256) void rope_kernel(const float* __restrict__ qsl,
                                                   const float* __restrict__ ksl,
                                                   const float* __restrict__ vsl,
                                                   bf16* __restrict__ qb,
                                                   bf16* __restrict__ kb,
                                                   bf16* __restrict__ vT,
                                                   const float* __restrict__ cosb,
                                                   const float* __restrict__ sinb,
                                                   const float* __restrict__ graw,
                                                   float* __restrict__ G)
{
    const int blk = blockIdx.x;
    if (blk < RQB + RKB) {
        int idx = blk * 256 + threadIdx.x;
        const float* src; size_t ssz; bf16* dst; int s, rem, stride;
        if (blk < RQB) {
            src = qsl; ssz = (size_t)S_LEN * HID; dst = qb; stride = HID;
            s = idx / (NH * 64); rem = idx % (NH * 64);
        } else {
            idx -= RQB * 256;
            src = ksl; ssz = (size_t)S_LEN * KVD; dst = kb; stride = KVD;
            s = idx / (NKV * 64); rem = idx % (NKV * 64);
        }
        int h = rem >> 6, d = rem & 63;
        size_t base = (size_t)s * stride + h * 128 + d;
        float x0 = src[base]      + src[ssz + base];
        float x1 = src[base + 64] + src[ssz + base + 64];
        float c0 = cosb[s * 128 + d], c1 = cosb[s * 128 + d + 64];
        float n0 = sinb[s * 128 + d], n1 = sinb[s * 128 + d + 64];
        dst[base]      = (bf16)(x0 * c0 - x1 * n0);
        dst[base + 64] = (bf16)(x1 * c1 + x0 * n1);
    } else if (blk < RQB + RKB + RVB) {
        int i = ((blk - RQB - RKB) * 256 + threadIdx.x) * 8;
        const size_t ssz = (size_t)S_LEN * KVD;
        bf16x8 r;
        #pragma unroll
        for (int x = 0; x < 8; ++x) r[x] = (bf16)(vsl[i + x] + vsl[ssz + i + x]);
        *(bf16x8*)&vT[i] = r;
    } else {                               // cumsum, one block per kv head
        const int c = blk - (RQB + RKB + RVB);
        const int t = threadIdx.x;
        __shared__ float sums[256];
        float loc[8];
        float run = 0.f;
        #pragma unroll
        for (int i = 0; i < 8; ++i) { run += graw[c * S_LEN + t * 8 + i]; loc[i] = run; }
        sums[t] = run;
        __syncthreads();
        for (int off = 1; off < 256; off <<= 1) {
            float add = (t >= off) ? sums[t - off] : 0.f;
            __syncthreads();
            sums[t] += add;
            __syncthreads();
        }
        float offset = sums[t] - run;
        #pragma unroll
        for (int i = 0; i < 8; ++i) G[c * S_LEN + t * 8 + i] = offset + loc[i];
    }
}

// ---------------------------------------------------------------------------
// Causal decay attention, j-split (unchanged from round 8).
// ---------------------------------------------------------------------------
__global__ __launch_bounds__(256) void attn_kernel(const bf16* __restrict__ q,
                                                   const bf16* __restrict__ k,
                                                   const bf16* __restrict__ vT,
                                                   const float* __restrict__ G,
                                                   bf16* __restrict__ out,
                                                   float* __restrict__ pO,
                                                   float* __restrict__ pden)
{
    int rem = blockIdx.x, qt = 0, cch = 0;
    #pragma unroll
    for (int g = 0; g < 4; ++g) {
        int sz = 8 * (g + 1);
        if (rem < sz) { qt = g * 8 + rem / (g + 1); cch = rem % (g + 1); break; }
        rem -= sz;
    }
    const int gg = qt >> 3, nc = gg + 1;
    const int jt0 = cch * 8, jt1 = min(qt + 1, jt0 + 8);

    const int h = blockIdx.y, kvh = h >> 2;
    const int qb = qt * 64;
    const int tid = threadIdx.x, w = tid >> 6, lane = tid & 63;
    const int l16 = lane & 15, quad = lane >> 4;

    __shared__ __attribute__((aligned(16))) bf16 Ks4[4][64][32];
    __shared__ __attribute__((aligned(16))) bf16 Vt4[2][128][32];
    __shared__ __attribute__((aligned(16))) bf16 Sb[4][16][68];

    bf16x8 qf[4];
    const int qrow = qb + w * 16 + l16;
    #pragma unroll
    for (int kc = 0; kc < 4; ++kc)
        qf[kc] = *(const bf16x8*)&q[(size_t)qrow * HID + h * HD + kc * 32 + quad * 8];

    const int irow = qb + w * 16 + quad * 4;
    float Gq[4];
    #pragma unroll
    for (int r = 0; r < 4; ++r) Gq[r] = G[kvh * S_LEN + irow + r];

    const int sr4 = lane >> 2, sc4 = (lane & 3) * 8;
    const int vkk = w >> 1, vdg = (w & 1) * 4;

    f32x4 acco[8] = {};
    float den[4] = {0.f, 0.f, 0.f, 0.f};

    for (int kt = jt0; kt < jt1; ++kt) {
        const int jb = kt * 64;
        __syncthreads();
        #pragma unroll
        for (int rg = 0; rg < 4; ++rg)
            gload_lds16(&k[(size_t)(jb + rg * 16 + sr4) * KVD + kvh * HD + w * 32 + sc4],
                        &Ks4[w][rg * 16][0]);
        #pragma unroll
        for (int it = 0; it < 4; ++it)
            gload_lds16(&vT[(size_t)(kvh * HD + (vdg + it) * 16 + sr4) * S_LEN + jb + vkk * 32 + sc4],
                        &Vt4[vkk][(vdg + it) * 16][0]);
        __syncthreads();

        f32x4 accs[4] = {};
        #pragma unroll
        for (int t = 0; t < 4; ++t)
            #pragma unroll
            for (int kc = 0; kc < 4; ++kc) {
                bf16x8 bfr = *(const bf16x8*)&Ks4[kc][t * 16 + l16][quad * 8];
                accs[t] = __builtin_amdgcn_mfma_f32_16x16x32_bf16(qf[kc], bfr, accs[t], 0, 0, 0);
            }

        const float Gt = G[kvh * S_LEN + jb];
        float sr[4];
        #pragma unroll
        for (int r = 0; r < 4; ++r) sr[r] = SCALE2 * __expf(Gq[r] - Gt);
        #pragma unroll
        for (int t = 0; t < 4; ++t) {
            int j = jb + t * 16 + l16;
            float colF = __expf(fminf(Gt - G[kvh * S_LEN + j], 85.f));
            #pragma unroll
            for (int r = 0; r < 4; ++r) {
                float d0 = accs[t][r];
                float sc = (j <= irow + r) ? d0 * d0 * sr[r] * colF : 0.f;
                den[r] += sc;
                Sb[w][quad * 4 + r][t * 16 + l16] = (bf16)sc;
            }
        }
        // no barrier: Sb[w] is wave-private

        #pragma unroll
        for (int kk = 0; kk < 2; ++kk) {
            bf16x8 af = *(const bf16x8*)&Sb[w][l16][kk * 32 + quad * 8];
            #pragma unroll
            for (int dt = 0; dt < 8; ++dt) {
                bf16x8 bfr = *(const bf16x8*)&Vt4[kk][dt * 16 + l16][quad * 8];
                acco[dt] = __builtin_amdgcn_mfma_f32_16x16x32_bf16(af, bfr, acco[dt], 0, 0, 0);
            }
        }
    }

    #pragma unroll
    for (int r = 0; r < 4; ++r) {
        #pragma unroll
        for (int off = 1; off < 16; off <<= 1) den[r] += __shfl_xor(den[r], off);
    }

    if (nc == 1) {
        float dinv[4];
        #pragma unroll
        for (int r = 0; r < 4; ++r) dinv[r] = 1.f / fmaxf(den[r], 1.f);
        #pragma unroll
        for (int dt = 0; dt < 8; ++dt)
            #pragma unroll
            for (int r = 0; r < 4; ++r)
                out[(size_t)(irow + r) * HID + h * HD + dt * 16 + l16] =
                    (bf16)(acco[dt][r] * dinv[r]);
    } else {
        const int slot = h * NCH + 4 * gg * (gg + 1) + (qt & 7) * (gg + 1) + cch;
        float* po = &pO[(size_t)slot * 8192];
        const int lr = w * 16 + quad * 4;
        #pragma unroll
        for (int dt = 0; dt < 8; ++dt)
            #pragma unroll
            for (int r = 0; r < 4; ++r)
                po[(lr + r) * 128 + dt * 16 + l16] = acco[dt][r];
        if (l16 == 0) {
            #pragma unroll
            for (int r = 0; r < 4; ++r) pden[slot * 64 + lr + r] = den[r];
        }
    }
}

// Combine partial chunks for qt >= 8. Grid: 16 heads x 24 qts.
__global__ __launch_bounds__(256) void attn_reduce_kernel(const float* __restrict__ pO,
                                                          const float* __restrict__ pden,
                                                          bf16* __restrict__ out)
{
    const int p = blockIdx.x;
    const int h = p / 24, qt = 8 + p % 24;
    const int gg = qt >> 3, nc = gg + 1;
    const int base = h * NCH + 4 * gg * (gg + 1) + (qt & 7) * (gg + 1);
    const int qb = qt * 64;
    const int tid = threadIdx.x;

    __shared__ float sden[64];
    if (tid < 64) {
        float s = 0.f;
        for (int c = 0; c < nc; ++c) s += pden[(base + c) * 64 + tid];
        sden[tid] = 1.f / fmaxf(s, 1.f);
    }
    __syncthreads();

    #pragma unroll
    for (int i = 0; i < 8; ++i) {
        int e = i * 1024 + tid * 4;
        float4 s = make_float4(0.f, 0.f, 0.f, 0.f);
        for (int c = 0; c < nc; ++c) {
            float4 v = *(const float4*)&pO[(size_t)(base + c) * 8192 + e];
            s.x += v.x; s.y += v.y; s.z += v.z; s.w += v.w;
        }
        int lr = e >> 7, col = e & 127;
        float di = sden[lr];
        bf16* o = &out[(size_t)(qb + lr) * HID + h * HD + col];
        o[0] = (bf16)(s.x * di); o[1] = (bf16)(s.y * di);
        o[2] = (bf16)(s.z * di); o[3] = (bf16)(s.w * di);
    }
}

// ---------------------------------------------------------------------------
extern "C" void kernel_launch(void* const* d_in, const int* in_sizes, int n_in,
                              void* d_out, int out_size, void* d_ws, size_t ws_size,
                              hipStream_t stream)
{
    const float* hs   = (const float*)d_in[0];
    const float* cosb = (const float*)d_in[1];
    const float* sinb = (const float*)d_in[2];
    const float* Wq   = (const float*)d_in[3];
    const float* Wk   = (const float*)d_in[4];
    const float* Wv   = (const float*)d_in[5];
    const float* Wg   = (const float*)d_in[6];
    const float* Wo   = (const float*)d_in[7];
    float* out = (float*)d_out;

    char* p = (char*)d_ws;
    bf16*  qbuf  = (bf16*)p;  p += (size_t)S_LEN * HID * 2;    // 8 MB
    bf16*  kbuf  = (bf16*)p;  p += (size_t)S_LEN * KVD * 2;    // 2 MB
    bf16*  vT    = (bf16*)p;  p += (size_t)S_LEN * KVD * 2;    // 2 MB ([KVD][S])
    bf16*  abuf  = (bf16*)p;  p += (size_t)S_LEN * HID * 2;    // 8 MB
    bf16*  hsb   = (bf16*)p;  p += (size_t)S_LEN * HID * 2;    // 8 MB
    bf16*  WcatT = (bf16*)p;  p += (size_t)NQKV * HID * 2;     // 12 MB
    bf16*  WoT   = (bf16*)p;  p += (size_t)HID * HID * 2;      // 8 MB
    float* graw  = (float*)p; p += (size_t)NKV * S_LEN * 4;
    float* G     = (float*)p; p += (size_t)NKV * S_LEN * 4;
    float* pO    = (float*)p; p += (size_t)NH * NCH * 8192 * 4; // 41.9 MB
    float* pden  = (float*)p; p += (size_t)NH * NCH * 64 * 4;   // 0.33 MB

    // qkv split-K slice buffers, phase-disjoint aliases:
    //   q slices 2x4M f32 + k slices 2x1M f32 = 40 MB on pO (41.9 MB);
    //   v slices 2x1M f32 = 8 MB on abuf (8 MB).
    // Written by gemm_qkv, consumed by rope — both strictly before attn
    // writes pO/abuf. No zero-init needed (plain stores).
    float* qsl = pO;                                  // [2][S*HID]
    float* ksl = pO + (size_t)8 * 1024 * 1024;        // [2][S*KVD]
    float* vsl = (float*)abuf;                        // [2][KVD*S]

    // 1: fused pre-pass (cvt + transposes + zero-out + gate projection)
    prep_kernel<<<7168, 256, 0, stream>>>(hs, Wq, Wk, Wv, Wo, Wg,
                                          hsb, WcatT, WoT, graw, out);
    // 2: fused QKV projection, split-K=2, plain f32 slice stores
    gemm_qkv_kernel<<<dim3(16, 24, 2), 256, 0, stream>>>(hsb, WcatT, qsl, ksl, vsl, S_LEN, HID);
    // 3: merged RoPE (slice-sum f32 -> bf16) + v cvt + gate cumsum
    rope_kernel<<<RQB + RKB + RVB + NKV, 256, 0, stream>>>(qsl, ksl, vsl, qbuf, kbuf, vT,
                                                           cosb, sinb, graw, G);
    // 4: j-split attention
    attn_kernel<<<dim3(NCH, NH), 256, 0, stream>>>(qbuf, kbuf, vT, G, abuf, pO, pden);
    // 5: combine
    attn_reduce_kernel<<<NH * 24, 256, 0, stream>>>(pO, pden, abuf);
    // 6: output projection (split-K=2, atomic into zeroed out)
    gemm_wo_kernel<<<dim3(16, 16, 2), 256, 0, stream>>>(abuf, WoT, out, S_LEN, HID, HID);
}